// Round 24
// baseline (726.506 us; speedup 1.0000x reference)
//
#include <hip/hip_runtime.h>

#define NN 64
#define NI 6
#define TT 1024
#define BB 1024
#define TB (TT * BB)
#define NSCALE 0.13416407864998738f        // sqrt(2/alpha) * sigma
#define ARNSCALE 0.013416407864998739f     // alpha * NSCALE
#define RREC 72                            // rnu record: 64 rn' (-> x) + 6 uterm + 2 pad(0)
#define BSTRIDE (TT * RREC)                // 73728 floats per batch

__device__ __forceinline__ float rdlane(float v, int l) {
    return __int_as_float(__builtin_amdgcn_readlane(__float_as_int(v), l));
}

// ---------------- Pass 1: build rnu[b][t][72] in d_ws ----------------
// record[0..63]  = ARNSCALE * rn[n][t][b]   (transposed, n contiguous)
// record[64..69] = u[i][t][b] + NSCALE*inn[i][t][b];  [70..71] = 0
__global__ __launch_bounds__(256) void build_rnu(
    const float* __restrict__ u,
    const float* __restrict__ rn,
    const float* __restrict__ inn,
    float* __restrict__ rnu)
{
    const int blk = blockIdx.x;
    const int t   = blk >> 4;
    const int b0  = (blk & 15) * 64;
    const int tid = threadIdx.x;

    __shared__ float lds[64][65];

    {   const int c  = tid & 63;
        const int r0 = tid >> 6;
#pragma unroll
        for (int it = 0; it < 16; ++it) {
            const int n = 4 * it + r0;
            lds[c][n] = ARNSCALE * rn[n * TB + t * BB + b0 + c];
        }
    }
    __syncthreads();
    {   const int cn = tid & 63;
        const int r0 = tid >> 6;
#pragma unroll
        for (int it = 0; it < 16; ++it) {
            const int r = 4 * it + r0;
            rnu[(b0 + r) * BSTRIDE + t * RREC + cn] = lds[r][cn];
        }
    }
    {   const int i  = tid & 7;
        const int br = tid >> 3;
#pragma unroll
        for (int it = 0; it < 2; ++it) {
            const int b = br + 32 * it;
            float v = 0.0f;
            if (i < NI) {
                const int g = i * TB + t * BB + b0 + b;
                v = fmaf(NSCALE, inn[g], u[g]);
            }
            rnu[(b0 + b) * BSTRIDE + t * RREC + 64 + i] = v;
        }
    }
}

// ---------------- Pass 2: recurrence, 2 batches/wave + store batching ----------------
// 512 blocks x 64 thr (2 waves/CU). Wave = 2 batches: half h = lane>>5, lane owns
// neurons n0=2p, n0+1 (full 64-float weight rows, pinned). One broadcast-read sweep
// (17 b128) serves BOTH batches (per-half uniform address) -> the ~350cyc LDS
// round-trip amortizes over 2 batch-steps and batch B's 140 fma fill batch A's
// latency shadow IN-WAVE (r14 measured 644 cyc/batch vs r23's 817). Stores are
// batched per 8-step chunk via register history (r23's vmcnt de-serialization).
__global__ __launch_bounds__(64, 1) void latent_rnn_w2(
    const float* __restrict__ rn_in,  // (B, T, 72) — reads
    float* __restrict__ x_out,        // (B, T, 72) — x writeback (same buffer)
    const float* __restrict__ Winp,   // (64, 6)
    const float* __restrict__ Wrec)   // (64, 64)
{
    const int hw = blockIdx.x;                   // 512 blocks
    const int g  = (hw & 7) * 64 + (hw >> 3);    // XCD swizzle: 128 batches/XCD
    const int n  = threadIdx.x;
    const int h  = n >> 5;                       // batch half
    const int p  = n & 31;
    const int n0 = 2 * p;                        // neurons n0, n0+1
    const int bb = 2 * g + h;

    // [chunk parity][row 0..7][2 batches x 96]: x[64] | ut[8] | pad
    __shared__ __align__(16) float xs[2][8][192];

    // ---- full-row weights for neurons n0, n0+1 (pinned) ----
    float w0[NN], w1[NN];
#pragma unroll
    for (int k = 0; k < NN; k += 4) {
        const float4 a = *reinterpret_cast<const float4*>(Wrec + n0 * NN + k);
        const float4 c = *reinterpret_cast<const float4*>(Wrec + (n0 + 1) * NN + k);
        w0[k] = a.x; w0[k+1] = a.y; w0[k+2] = a.z; w0[k+3] = a.w;
        w1[k] = c.x; w1[k+1] = c.y; w1[k+2] = c.z; w1[k+3] = c.w;
    }
    float wi0[NI], wi1[NI];
#pragma unroll
    for (int i = 0; i < NI; ++i) {
        wi0[i] = Winp[n0 * NI + i];
        wi1[i] = Winp[(n0 + 1) * NI + i];
    }
#pragma unroll
    for (int k = 0; k < NN; ++k) { asm volatile("" : "+v"(w0[k])); asm volatile("" : "+v"(w1[k])); }
#pragma unroll
    for (int i = 0; i < NI; ++i) { asm volatile("" : "+v"(wi0[i])); asm volatile("" : "+v"(wi1[i])); }

    const float* rptr = rn_in + bb * BSTRIDE + n0;            // rn' pair view (b64)
    const float* uptr = rn_in + bb * BSTRIDE + 64 + (p & 7);  // uterm view (p<8 live)
    float*       xdst = x_out + bb * BSTRIDE + n0;            // x pair writeback

    // ---- init: row read by step 0 = parity1 row7: x[0]=0, ut=uterm(0) ----
    *reinterpret_cast<float2*>(&xs[1][7][h * 96 + n0]) = make_float2(0.f, 0.f);
    if (p < 8) xs[1][7][h * 96 + 64 + p] = uptr[0];

    // prefetch rings depth 4: rnb = rn'(t) pair, utb = uterm(t+1)
    float2 rnb[4];
    float  utb[4];
#pragma unroll
    for (int d = 0; d < 4; ++d) {
        rnb[d] = *reinterpret_cast<const float2*>(rptr + d * RREC);
        utb[d] = uptr[(d + 1) * RREC];
    }

    float x0 = 0.0f, x1 = 0.0f;
    float xh0[8], xh1[8];   // register history, static indices only

#define STEP(tcur, slot, J, RD, WR, TP, TQ)                                   \
    do {                                                                      \
        const float2 rcur = rnb[slot];                                        \
        const float  ucur = utb[slot];                                        \
        rnb[slot] = *reinterpret_cast<const float2*>(rptr + (TP) * RREC);     \
        utb[slot] = uptr[(TQ) * RREC];                                        \
        const float* row = (RD) + h * 96;                                     \
        const float4* xr = reinterpret_cast<const float4*>(row);              \
        float a0=0.f,a1=0.f,a2=0.f,a3=0.f, c0=0.f,c1=0.f,c2=0.f,c3=0.f;       \
        _Pragma("unroll")                                                     \
        for (int q = 0; q < 16; ++q) {                                        \
            const float4 v = xr[q];                                           \
            a0 = fmaf(v.x, w0[4*q+0], a0); c0 = fmaf(v.x, w1[4*q+0], c0);     \
            a1 = fmaf(v.y, w0[4*q+1], a1); c1 = fmaf(v.y, w1[4*q+1], c1);     \
            a2 = fmaf(v.z, w0[4*q+2], a2); c2 = fmaf(v.z, w1[4*q+2], c2);     \
            a3 = fmaf(v.w, w0[4*q+3], a3); c3 = fmaf(v.w, w1[4*q+3], c3);     \
        }                                                                     \
        const float4 u0v = xr[16];                                            \
        const float2 u1v = *reinterpret_cast<const float2*>(row + 68);        \
        a0 = fmaf(u0v.x, wi0[0], a0); c0 = fmaf(u0v.x, wi1[0], c0);           \
        a1 = fmaf(u0v.y, wi0[1], a1); c1 = fmaf(u0v.y, wi1[1], c1);           \
        a2 = fmaf(u0v.z, wi0[2], a2); c2 = fmaf(u0v.z, wi1[2], c2);           \
        a3 = fmaf(u0v.w, wi0[3], a3); c3 = fmaf(u0v.w, wi1[3], c3);           \
        a0 = fmaf(u1v.x, wi0[4], a0); c0 = fmaf(u1v.x, wi1[4], c0);           \
        a1 = fmaf(u1v.y, wi0[5], a1); c1 = fmaf(u1v.y, wi1[5], c1);           \
        const float pre0 = (a0 + a1) + (a2 + a3);                             \
        const float pre1 = (c0 + c1) + (c2 + c3);                             \
        const float xn0 = fmaf(0.9f, x0, fmaf(0.1f, fmaxf(pre0, 0.f), rcur.x)); \
        const float xn1 = fmaf(0.9f, x1, fmaf(0.1f, fmaxf(pre1, 0.f), rcur.y)); \
        x0 = xn0; x1 = xn1;                                                   \
        *reinterpret_cast<float2*>((WR) + h * 96 + n0) = make_float2(xn0, xn1); \
        if (p < 8) (WR)[h * 96 + 64 + p] = ucur;                              \
        xh0[J] = xn0; xh1[J] = xn1;                                           \
    } while (0)

    // ---- 127 full chunks of 8 steps (t = 0..1015); prefetch unclamped ----
#pragma unroll 1
    for (int c = 0; c < 127; ++c) {
        const int t0 = c << 3;
        float*       B  = &xs[c & 1][0][0];         // row stride 192
        const float* R0 = &xs[(c + 1) & 1][7][0];
        STEP(t0 + 0, 0, 0, R0,        B + 0*192, t0 + 4,  t0 + 5);
        STEP(t0 + 1, 1, 1, B + 0*192, B + 1*192, t0 + 5,  t0 + 6);
        STEP(t0 + 2, 2, 2, B + 1*192, B + 2*192, t0 + 6,  t0 + 7);
        STEP(t0 + 3, 3, 3, B + 2*192, B + 3*192, t0 + 7,  t0 + 8);
        STEP(t0 + 4, 0, 4, B + 3*192, B + 4*192, t0 + 8,  t0 + 9);
        STEP(t0 + 5, 1, 5, B + 4*192, B + 5*192, t0 + 9,  t0 + 10);
        STEP(t0 + 6, 2, 6, B + 5*192, B + 6*192, t0 + 10, t0 + 11);
        STEP(t0 + 7, 3, 7, B + 6*192, B + 7*192, t0 + 11, t0 + 12);
        // batched flush: 8 coalesced float2 stores, off the per-step path
#pragma unroll
        for (int jj = 0; jj < 8; ++jj)
            *reinterpret_cast<float2*>(xdst + (t0 + jj) * RREC) =
                make_float2(xh0[jj], xh1[jj]);
    }

    // ---- tail chunk: t = 1016..1022 (7 steps), clamped prefetch ----
    {
        float*       B  = &xs[1][0][0];
        const float* R0 = &xs[0][7][0];
#define TC(tc) (((tc) + 4 < TT) ? (tc) + 4 : TT - 1)
#define TQ2(tc) (((tc) + 5 < TT) ? (tc) + 5 : TT - 1)
        STEP(1016, 0, 0, R0,        B + 0*192, TC(1016), TQ2(1016));
        STEP(1017, 1, 1, B + 0*192, B + 1*192, TC(1017), TQ2(1017));
        STEP(1018, 2, 2, B + 1*192, B + 2*192, TC(1018), TQ2(1018));
        STEP(1019, 3, 3, B + 2*192, B + 3*192, TC(1019), TQ2(1019));
        STEP(1020, 0, 4, B + 3*192, B + 4*192, TC(1020), TQ2(1020));
        STEP(1021, 1, 5, B + 4*192, B + 5*192, TC(1021), TQ2(1021));
        STEP(1022, 2, 6, B + 5*192, B + 6*192, TC(1022), TQ2(1022));
#undef TC
#undef TQ2
#pragma unroll
        for (int jj = 0; jj < 7; ++jj)
            *reinterpret_cast<float2*>(xdst + (1016 + jj) * RREC) =
                make_float2(xh0[jj], xh1[jj]);
    }
#undef STEP
}

// ---------------- Pass 3: transpose + fused output projection ----------------
// states[n][t][b] = (t==0) ? 0 : rnu[b][t-1][n];  outputs = states @ Wout^T.
__global__ __launch_bounds__(256) void trans_out(
    const float* __restrict__ rnu,
    const float* __restrict__ Wout,     // (2, 64)
    float* __restrict__ states,         // (64, T, B)
    float* __restrict__ outputs)        // (2, T, B)
{
    const int blk = blockIdx.x;
    const int t   = blk >> 4;
    const int b0  = (blk & 15) * 64;
    const int tid = threadIdx.x;

    __shared__ float xt[64][65];   // [b][n]
    __shared__ float wo[2][64];

    if (tid < 128) wo[tid >> 6][tid & 63] = Wout[tid];

    const int col = tid & 63;
    const int r0  = tid >> 6;
    if (t == 0) {
#pragma unroll
        for (int it = 0; it < 16; ++it) xt[4 * it + r0][col] = 0.0f;
    } else {
#pragma unroll
        for (int it = 0; it < 16; ++it) {
            const int r = 4 * it + r0;
            xt[r][col] = rnu[(b0 + r) * BSTRIDE + (t - 1) * RREC + col];
        }
    }
    __syncthreads();

#pragma unroll
    for (int it = 0; it < 16; ++it) {
        const int n = 4 * it + r0;
        states[n * TB + t * BB + b0 + col] = xt[col][n];
    }

    if (tid < 128) {
        const int o  = tid >> 6;
        const int bb = tid & 63;
        float acc = 0.0f;
#pragma unroll
        for (int k = 0; k < NN; ++k) acc = fmaf(xt[bb][k], wo[o][k], acc);
        outputs[o * TB + t * BB + b0 + bb] = acc;
    }
}

// ---------------- Fallback (no-workspace path, proven correct) ----------------
#define BARRIER() do {                                                        \
    __builtin_amdgcn_sched_barrier(0);                                        \
    asm volatile("s_waitcnt lgkmcnt(0)\n\ts_barrier" ::: "memory");           \
    __builtin_amdgcn_sched_barrier(0);                                        \
} while (0)

__global__ __launch_bounds__(256, 1) void latent_rnn_fb(
    const float* __restrict__ u, const float* __restrict__ rn,
    const float* __restrict__ inn, const float* __restrict__ Winp,
    const float* __restrict__ Wrec, float* __restrict__ states)
{
    const int hw  = blockIdx.x;
    const int lb  = (hw & 7) * 32 + (hw >> 3);
    const int b0  = lb * 4;
    const int tid = threadIdx.x;
    const int l   = tid & 63;
    const int w   = tid >> 6;
    const int n   = tid >> 2;
    const int bs  = tid & 3;

    __shared__ float rnT[2][NN][5];
    __shared__ float xT[2][NN][5];
    __shared__ float iT[2][4][8];

    float wreg[NN];
#pragma unroll
    for (int k = 0; k < NN; k += 4) {
        const float4 w4 = *reinterpret_cast<const float4*>(Wrec + l * NN + k);
        wreg[k] = w4.x; wreg[k+1] = w4.y; wreg[k+2] = w4.z; wreg[k+3] = w4.w;
    }
    float wi[NI];
#pragma unroll
    for (int i = 0; i < NI; ++i) wi[i] = Winp[l * NI + i];

    const float* rsrc = rn + n * TB + b0 + bs;
    float*       sdst = states + n * TB + b0 + bs;
    const bool  ist  = (tid < NI * 4);
    const int   ii   = tid >> 2;
    const int   ib   = tid & 3;
    const float* usrc = u   + ii * TB + b0 + ib;
    const float* isrc = inn + ii * TB + b0 + ib;

    rnT[0][n][bs] = rsrc[0];
    if (ist) iT[0][ib][ii] = fmaf(NSCALE, isrc[0], usrc[0]);
    xT[0][l][w] = 0.0f;

    float rnPF[4], uPF[4], iPF[4];
#pragma unroll
    for (int dd = 0; dd < 4; ++dd) {
        rnPF[dd] = rsrc[(dd + 1) * BB];
        if (ist) { uPF[dd] = usrc[(dd + 1) * BB]; iPF[dd] = isrc[(dd + 1) * BB]; }
    }
    __syncthreads();

    float xreg = 0.0f;

#define FSTEP(tcur, slot, CC)                                                 \
  {                                                                           \
    sdst[(tcur) * BB] = xT[CC][n][bs];                                        \
    const float rcur = rnT[CC][l][w];                                         \
    const float4 iv0 = *reinterpret_cast<const float4*>(&iT[CC][w][0]);       \
    const float2 iv1 = *reinterpret_cast<const float2*>(&iT[CC][w][4]);       \
    float a0 = 0.f, a1 = 0.f, a2 = 0.f, a3 = 0.f;                             \
    _Pragma("unroll")                                                         \
    for (int k = 0; k < NN; k += 4) {                                         \
        a0 = fmaf(rdlane(xreg, k + 0), wreg[k + 0], a0);                      \
        a1 = fmaf(rdlane(xreg, k + 1), wreg[k + 1], a1);                      \
        a2 = fmaf(rdlane(xreg, k + 2), wreg[k + 2], a2);                      \
        a3 = fmaf(rdlane(xreg, k + 3), wreg[k + 3], a3);                      \
    }                                                                         \
    a0 = fmaf(iv0.x, wi[0], a0); a1 = fmaf(iv0.y, wi[1], a1);                 \
    a2 = fmaf(iv0.z, wi[2], a2); a3 = fmaf(iv0.w, wi[3], a3);                 \
    a0 = fmaf(iv1.x, wi[4], a0); a1 = fmaf(iv1.y, wi[5], a1);                 \
    const float pre = (a0 + a1) + (a2 + a3);                                  \
    const float xn  = fmaf(0.9f, xreg,                                        \
                           fmaf(0.1f, fmaxf(pre, 0.f), ARNSCALE * rcur));     \
    xreg = xn;                                                                \
    xT[(CC) ^ 1][l][w] = xn;                                                  \
    rnT[(CC) ^ 1][n][bs] = rnPF[slot];                                        \
    if (ist) iT[(CC) ^ 1][ib][ii] = fmaf(NSCALE, iPF[slot], uPF[slot]);       \
    { int tp = (tcur) + 5; if (tp > TT - 2) tp = TT - 2;                      \
      rnPF[slot] = rsrc[tp * BB];                                             \
      if (ist) { uPF[slot] = usrc[tp * BB]; iPF[slot] = isrc[tp * BB]; } }    \
    BARRIER();                                                                \
  }

#pragma unroll 1
    for (int t = 0; t < 1020; t += 4) {
        FSTEP(t + 0, 0, 0);
        FSTEP(t + 1, 1, 1);
        FSTEP(t + 2, 2, 0);
        FSTEP(t + 3, 3, 1);
    }
    FSTEP(1020, 0, 0);
    FSTEP(1021, 1, 1);
    FSTEP(1022, 2, 0);
#undef FSTEP

    sdst[(TT - 1) * BB] = xT[1][n][bs];
}

__global__ __launch_bounds__(256) void out_proj(
    const float* __restrict__ states,
    const float* __restrict__ Wout,
    float* __restrict__ outputs)
{
    const int g4 = (blockIdx.x * 256 + threadIdx.x) * 4;
    float4 a0 = {0.f, 0.f, 0.f, 0.f};
    float4 a1 = {0.f, 0.f, 0.f, 0.f};
#pragma unroll
    for (int k = 0; k < NN; ++k) {
        const float4 s = *reinterpret_cast<const float4*>(states + k * TB + g4);
        const float w0 = Wout[k];
        const float w1 = Wout[NN + k];
        a0.x = fmaf(s.x, w0, a0.x); a0.y = fmaf(s.y, w0, a0.y);
        a0.z = fmaf(s.z, w0, a0.z); a0.w = fmaf(s.w, w0, a0.w);
        a1.x = fmaf(s.x, w1, a1.x); a1.y = fmaf(s.y, w1, a1.y);
        a1.z = fmaf(s.z, w1, a1.z); a1.w = fmaf(s.w, w1, a1.w);
    }
    *reinterpret_cast<float4*>(outputs + g4)      = a0;
    *reinterpret_cast<float4*>(outputs + TB + g4) = a1;
}

extern "C" void kernel_launch(void* const* d_in, const int* in_sizes, int n_in,
                              void* d_out, int out_size, void* d_ws, size_t ws_size,
                              hipStream_t stream) {
    const float* u    = (const float*)d_in[0];
    const float* rn   = (const float*)d_in[1];
    const float* inn  = (const float*)d_in[2];
    const float* Winp = (const float*)d_in[3];
    const float* Wrec = (const float*)d_in[4];
    const float* Wout = (const float*)d_in[5];

    float* states  = (float*)d_out;                          // 64*1024*1024
    float* outputs = (float*)d_out + (size_t)NN * TT * BB;   // 2*1024*1024

    const size_t need = (size_t)BB * TT * RREC * sizeof(float);  // ~302 MB
    if (ws_size >= need) {
        float* rnu = (float*)d_ws;
        build_rnu<<<TT * 16, 256, 0, stream>>>(u, rn, inn, rnu);
        latent_rnn_w2<<<512, 64, 0, stream>>>(rnu, rnu, Winp, Wrec);
        trans_out<<<TT * 16, 256, 0, stream>>>(rnu, Wout, states, outputs);
    } else {
        latent_rnn_fb<<<256, 256, 0, stream>>>(u, rn, inn, Winp, Wrec, states);
        out_proj<<<1024, 256, 0, stream>>>(states, Wout, outputs);
    }
}